// Round 6
// baseline (20034.050 us; speedup 1.0000x reference)
//
#include <hip/hip_runtime.h>
#include <math.h>

#define BB 64      // batch
#define SS 512     // seq len
#define EE 128     // embed dim
#define HH 256     // hidden
#define NC 9       // classes
#define G4 1024    // 4*H gates (one direction)
#define TCLOG 7
#define TC 128     // time chunk
#define NCH (SS / TC)

// ---------- activations (overflow-safe, fast) ----------
__device__ __forceinline__ float sigf(float x) {
    return 1.0f / (1.0f + __expf(-x));
}
__device__ __forceinline__ float tanhfast(float x) {
    float a = fabsf(x);
    float e = __expf(-2.0f * a);
    float t = (1.0f - e) / (1.0f + e);
    return copysignf(t, x);
}

// ---------- transpose w_hh -> wT[dir][k4][j][4] for coalesced f4 loads ----------
__global__ void transpose_whh(const float* __restrict__ whh, float* __restrict__ wT) {
    // whh: [2][1024][256] ; wT: [2][64][1024][4]
    int idx = blockIdx.x * 256 + threadIdx.x;
    if (idx >= 2 * 64 * 1024) return;
    int jj  = idx & 1023;
    int k4  = (idx >> 10) & 63;
    int dir = idx >> 16;
    float4 v = *(const float4*)(whh + ((long)(dir * 1024 + jj)) * 256 + (k4 << 2));
    *(float4*)(wT + (((long)(dir * 64 + k4)) * 1024 + jj) * 4) = v;
}

// ---------- tiled f32 GEMM (proven): out[m][n] = A . W[n] + bias ----------
template <int KDIM, bool GATHER>
__global__ __launch_bounds__(256) void gemm_xg(
    const float* __restrict__ A, const int* __restrict__ tokens,
    const float* __restrict__ W, const float* __restrict__ bias,
    float* __restrict__ out, int t_base, int t_sign)
{
    __shared__ float As[16][68];
    __shared__ float Bs[16][68];
    const int tid = threadIdx.x;
    const int m0 = blockIdx.x * 64;
    const int n0 = blockIdx.y * 64;

    const int lr = tid >> 2;
    const int lk = (tid & 3) * 4;
    const int mload = m0 + lr;
    const int tcc = mload & (TC - 1);
    const int b   = mload >> TCLOG;
    const int tglob = t_base + t_sign * tcc;
    const long arow = (long)b * SS + tglob;
    const float* Ap = GATHER ? (A + (long)tokens[arow] * KDIM + lk)
                             : (A + arow * (long)KDIM + lk);
    const float* Wp = W + (long)(n0 + lr) * KDIM + lk;

    const int tr = tid >> 4;
    const int tn = tid & 15;

    float acc[4][4];
    #pragma unroll
    for (int i = 0; i < 4; i++)
        #pragma unroll
        for (int j = 0; j < 4; j++) acc[i][j] = 0.f;

    #pragma unroll 1
    for (int k0 = 0; k0 < KDIM; k0 += 16) {
        float4 av = *(const float4*)(Ap + k0);
        float4 bv = *(const float4*)(Wp + k0);
        As[lk + 0][lr] = av.x; As[lk + 1][lr] = av.y;
        As[lk + 2][lr] = av.z; As[lk + 3][lr] = av.w;
        Bs[lk + 0][lr] = bv.x; Bs[lk + 1][lr] = bv.y;
        Bs[lk + 2][lr] = bv.z; Bs[lk + 3][lr] = bv.w;
        __syncthreads();
        #pragma unroll
        for (int kk = 0; kk < 16; kk++) {
            float a[4], w[4];
            *(float4*)a = *(const float4*)&As[kk][tr * 4];
            *(float4*)w = *(const float4*)&Bs[kk][tn * 4];
            #pragma unroll
            for (int i = 0; i < 4; i++)
                #pragma unroll
                for (int j = 0; j < 4; j++) acc[i][j] = fmaf(a[i], w[j], acc[i][j]);
        }
        __syncthreads();
    }

    float4 bc = *(const float4*)(bias + n0 + tn * 4);
    #pragma unroll
    for (int i = 0; i < 4; i++) {
        float4 r;
        r.x = acc[i][0] + bc.x; r.y = acc[i][1] + bc.y;
        r.z = acc[i][2] + bc.z; r.w = acc[i][3] + bc.w;
        *(float4*)(out + (long)(m0 + tr * 4 + i) * G4 + n0 + tn * 4) = r;
    }
}

// ---------- register-resident LSTM scan ----------
// Grid (64 batch, 2 dir), 1024 threads. Thread j owns gate row j:
// its 256 w_hh weights live in 64 float4 VGPRs (capped 512 by launch_bounds).
// h broadcast via LDS (uniform-address ds_read_b128 = conflict-free).
// No cross-block communication; per-step sync = 2x __syncthreads.
__global__ __launch_bounds__(1024, 4) void lstm_rscan(
    const float* __restrict__ xgF, const float* __restrict__ xgB, // [B][TC][1024]
    const float* __restrict__ wT,     // [2][64][1024][4]
    const float* __restrict__ bhh2,   // [2][1024]
    float* __restrict__ hout,         // [B*S][512]
    float* __restrict__ state,        // [2][B][2][256]
    int tbF, int tbB, int doInit)
{
    const int b = blockIdx.x;
    const int d = blockIdx.y;
    const int j = threadIdx.x;
    const float* xg = (d ? xgB : xgF) + (long)b * TC * G4 + j;
    const float* wp = wT + (long)d * 64 * 1024 * 4 + j * 4;

    __shared__ float hl[HH];
    __shared__ float gl[G4];

    // weights -> 256 VGPRs (64 x float4); per k4 a wave reads 1KB contiguous
    float4 w4[64];
    #pragma unroll
    for (int k4 = 0; k4 < 64; k4++)
        w4[k4] = *(const float4*)(wp + (long)k4 * 4096);

    const float bj = bhh2[d * G4 + j];
    float c_reg = 0.f;
    if (doInit) {
        if (j < HH) hl[j] = 0.f;
    } else {
        if (j < HH) {
            hl[j] = state[((d * BB + b) * 2 + 0) * HH + j];
            c_reg = state[((d * BB + b) * 2 + 1) * HH + j];
        }
    }
    __syncthreads();

    for (int tc = 0; tc < TC; ++tc) {
        float acc = xg[(long)tc * G4] + bj;
        const float4* hl4 = (const float4*)hl;
        #pragma unroll
        for (int k4 = 0; k4 < 64; ++k4) {
            float4 h4 = hl4[k4];
            acc = fmaf(w4[k4].x, h4.x, acc);
            acc = fmaf(w4[k4].y, h4.y, acc);
            acc = fmaf(w4[k4].z, h4.z, acc);
            acc = fmaf(w4[k4].w, h4.w, acc);
        }
        gl[j] = acc;
        __syncthreads();                  // all hl reads + gl writes done
        if (j < HH) {
            float gi = gl[j], gf = gl[j + 256], gg = gl[j + 512], go = gl[j + 768];
            c_reg = sigf(gf) * c_reg + sigf(gi) * tanhfast(gg);
            float h = sigf(go) * tanhfast(c_reg);
            hl[j] = h;
            int t = d ? (tbB - tc) : (tbF + tc);
            hout[((long)(b * SS + t)) * 512 + d * HH + j] = h;
        }
        __syncthreads();                  // new hl visible
    }
    if (j < HH) {
        state[((d * BB + b) * 2 + 0) * HH + j] = hl[j];
        state[((d * BB + b) * 2 + 1) * HH + j] = c_reg;
    }
}

// ---------- emissions ----------
__global__ __launch_bounds__(256) void emissions_k(
    const float* __restrict__ h1, const float* __restrict__ clsw,
    const float* __restrict__ clsb, float* __restrict__ em)
{
    long u = (long)blockIdx.x * 256 + threadIdx.x;
    if (u >= (long)BB * SS * NC) return;
    int c = (int)(u % NC);
    long m = u / NC;
    const float4* hr = (const float4*)(h1 + m * 512);
    const float4* wr = (const float4*)(clsw + (long)c * 512);
    float s0 = 0, s1 = 0, s2 = 0, s3 = 0;
    #pragma unroll 8
    for (int q = 0; q < 128; q += 4) {
        float4 a0 = hr[q],     w0 = wr[q];
        float4 a1 = hr[q + 1], w1 = wr[q + 1];
        float4 a2 = hr[q + 2], w2 = wr[q + 2];
        float4 a3 = hr[q + 3], w3 = wr[q + 3];
        s0 += a0.x * w0.x + a0.y * w0.y + a0.z * w0.z + a0.w * w0.w;
        s1 += a1.x * w1.x + a1.y * w1.y + a1.z * w1.z + a1.w * w1.w;
        s2 += a2.x * w2.x + a2.y * w2.y + a2.z * w2.z + a2.w * w2.w;
        s3 += a3.x * w3.x + a3.y * w3.y + a3.z * w3.z + a3.w * w3.w;
    }
    em[u] = (s0 + s1) + (s2 + s3) + clsb[c];
}

// ---------- CRF log-likelihood per batch row ----------
__global__ __launch_bounds__(64) void crf_llh(
    const float* __restrict__ em, const int* __restrict__ labels,
    const int* __restrict__ mask, const float* __restrict__ start,
    const float* __restrict__ endt, const float* __restrict__ trans,
    float* __restrict__ llh)
{
    int b = blockIdx.x, j = threadIdx.x;
    bool act = j < NC;
    float tcol[NC];
    #pragma unroll
    for (int i = 0; i < NC; i++) tcol[i] = act ? trans[i * NC + j] : 0.f;
    const float* emb_ = em + (long)b * SS * NC;
    const int* lb = labels + b * SS;
    const int* mk = mask + b * SS;
    float alpha = act ? (start[j] + emb_[j]) : -1e30f;

    float num = 0.f;
    int msum = 0;
    for (int t = j; t < SS; t += 64) msum += (mk[t] != 0);
    for (int t = 1 + j; t < SS; t += 64) {
        float m = (float)mk[t];
        num += m * (trans[lb[t - 1] * NC + lb[t]] + emb_[t * NC + lb[t]]);
    }
    for (int o = 32; o > 0; o >>= 1) {
        num  += __shfl_down(num, o);
        msum += __shfl_down(msum, o);
    }
    msum = __shfl(msum, 0);

    for (int t = 1; t < SS; t++) {
        int m = mk[t];
        float emj = act ? emb_[t * NC + j] : 0.f;
        float v[NC];
        float mx = -1e30f;
        #pragma unroll
        for (int i = 0; i < NC; i++) {
            v[i] = __shfl(alpha, i) + tcol[i];
            mx = fmaxf(mx, v[i]);
        }
        float sum = 0.f;
        #pragma unroll
        for (int i = 0; i < NC; i++) sum += __expf(v[i] - mx);
        float nxt = mx + __logf(sum) + emj;
        if (m > 0 && act) alpha = nxt;
    }
    float fin = act ? alpha + endt[j] : -1e30f;
    float mx = -1e30f;
    #pragma unroll
    for (int i = 0; i < NC; i++) mx = fmaxf(mx, __shfl(fin, i));
    float s = 0.f;
    #pragma unroll
    for (int i = 0; i < NC; i++) s += __expf(__shfl(fin, i) - mx);
    float den = mx + __logf(s);
    if (j == 0) {
        int last_idx = msum - 1;
        float numer = num + start[lb[0]] + emb_[lb[0]] + endt[lb[last_idx]];
        llh[b] = numer - den;
    }
}

__global__ __launch_bounds__(64) void loss_k(const float* __restrict__ llh, float* __restrict__ out) {
    int j = threadIdx.x;
    float v = llh[j];
    for (int o = 32; o > 0; o >>= 1) v += __shfl_down(v, o);
    if (j == 0) out[0] = -v / 64.0f;
}

// ---------- Viterbi per batch row ----------
__global__ __launch_bounds__(64) void viterbi_k(
    const float* __restrict__ em, const int* __restrict__ mask,
    const float* __restrict__ start, const float* __restrict__ endt,
    const float* __restrict__ trans, float* __restrict__ outp)
{
    int b = blockIdx.x, j = threadIdx.x;
    bool act = j < NC;
    __shared__ unsigned char bp[SS][NC];
    float tcol[NC];
    #pragma unroll
    for (int i = 0; i < NC; i++) tcol[i] = act ? trans[i * NC + j] : 0.f;
    const float* emb_ = em + (long)b * SS * NC;
    const int* mk = mask + b * SS;
    float score = act ? (start[j] + emb_[j]) : -1e30f;

    for (int t = 1; t < SS; t++) {
        float best = 0.f;
        int bi = 0;
        #pragma unroll
        for (int i = 0; i < NC; i++) {
            float vv = __shfl(score, i) + tcol[i];
            if (i == 0 || vv > best) { best = vv; bi = i; }   // first-max (jnp.argmax)
        }
        int m = mk[t];
        float nxt = best + (act ? emb_[t * NC + j] : 0.f);
        if (act) {
            if (m > 0) { score = nxt; bp[t][j] = (unsigned char)bi; }
            else       { bp[t][j] = (unsigned char)j; }
        }
    }
    float fin = act ? score + endt[j] : -1e30f;
    float bestf = 0.f;
    int last = 0;
    #pragma unroll
    for (int i = 0; i < NC; i++) {
        float vv = __shfl(fin, i);
        if (i == 0 || vv > bestf) { bestf = vv; last = i; }
    }
    __syncthreads();
    if (j == 0) {
        int cur = last;
        outp[1 + (long)b * SS + (SS - 1)] = (float)cur;
        for (int t = SS - 1; t >= 1; t--) {
            cur = bp[t][cur];
            outp[1 + (long)b * SS + (t - 1)] = (float)cur;
        }
    }
}

extern "C" void kernel_launch(void* const* d_in, const int* in_sizes, int n_in,
                              void* d_out, int out_size, void* d_ws, size_t ws_size,
                              hipStream_t stream) {
    const int*   tok    = (const int*)d_in[0];
    const int*   lab    = (const int*)d_in[1];
    const int*   msk    = (const int*)d_in[2];
    const float* emb    = (const float*)d_in[3];
    const float* w_ih0  = (const float*)d_in[4];   // (2,1024,128)
    const float* w_hh0  = (const float*)d_in[5];   // (2,1024,256)
    const float* b_ih0  = (const float*)d_in[6];   // (2,1024)
    const float* b_hh0  = (const float*)d_in[7];
    const float* w_ih1  = (const float*)d_in[8];   // (2,1024,512)
    const float* w_hh1  = (const float*)d_in[9];
    const float* b_ih1  = (const float*)d_in[10];
    const float* b_hh1  = (const float*)d_in[11];
    const float* clsw   = (const float*)d_in[12];  // (9,512)
    const float* clsb   = (const float*)d_in[13];
    const float* startt = (const float*)d_in[14];
    const float* endt   = (const float*)d_in[15];
    const float* transm = (const float*)d_in[16];
    float* out = (float*)d_out;

    // ---- workspace carve (f32 elements); ~205 MB (round-3-proven footprint) ----
    size_t nH  = (size_t)BB * SS * 512;            // 16.78M each
    size_t nWT = (size_t)2 * 64 * 1024 * 4;        // 0.52M per layer
    size_t nEM = (size_t)BB * SS * NC;
    size_t nST = (size_t)2 * BB * 2 * HH;
    size_t nXG = (size_t)BB * TC * G4;             // 8.39M each dir

    float* H0  = (float*)d_ws;
    float* H1  = H0 + nH;
    float* WT0 = H1 + nH;
    float* WT1 = WT0 + nWT;
    float* EM  = WT1 + nWT;
    float* ST  = EM + nEM;
    float* LLH = ST + nST;
    float* XGF = LLH + 64;
    float* XGB = XGF + nXG;

    transpose_whh<<<512, 256, 0, stream>>>(w_hh0, WT0);
    transpose_whh<<<512, 256, 0, stream>>>(w_hh1, WT1);

    dim3 gg((BB * TC) / 64, G4 / 64);    // (128, 16)
    dim3 rg(BB, 2);                      // 128 blocks

    // ---- layer 0 ----
    for (int c = 0; c < NCH; c++) {
        int tbF = c * TC;
        int tbB = SS - 1 - c * TC;
        gemm_xg<128, true><<<gg, 256, 0, stream>>>(emb, tok, w_ih0,              b_ih0,        XGF, tbF, +1);
        gemm_xg<128, true><<<gg, 256, 0, stream>>>(emb, tok, w_ih0 + 1024 * 128, b_ih0 + 1024, XGB, tbB, -1);
        lstm_rscan<<<rg, 1024, 0, stream>>>(XGF, XGB, WT0, b_hh0, H0, ST, tbF, tbB, c == 0);
    }
    // ---- layer 1 ----
    for (int c = 0; c < NCH; c++) {
        int tbF = c * TC;
        int tbB = SS - 1 - c * TC;
        gemm_xg<512, false><<<gg, 256, 0, stream>>>(H0, nullptr, w_ih1,              b_ih1,        XGF, tbF, +1);
        gemm_xg<512, false><<<gg, 256, 0, stream>>>(H0, nullptr, w_ih1 + 1024 * 512, b_ih1 + 1024, XGB, tbB, -1);
        lstm_rscan<<<rg, 1024, 0, stream>>>(XGF, XGB, WT1, b_hh1, H1, ST, tbF, tbB, c == 0);
    }

    emissions_k<<<((BB * SS * NC) + 255) / 256, 256, 0, stream>>>(H1, clsw, clsb, EM);
    crf_llh<<<BB, 64, 0, stream>>>(EM, lab, msk, startt, endt, transm, LLH);
    loss_k<<<1, 64, 0, stream>>>(LLH, out);
    viterbi_k<<<BB, 64, 0, stream>>>(EM, msk, startt, endt, transm, out);
}

// Round 7
// 14093.040 us; speedup vs baseline: 1.4216x; 1.4216x over previous
//
#include <hip/hip_runtime.h>
#include <math.h>

#define BB 64      // batch
#define SS 512     // seq len
#define EE 128     // embed dim
#define HH 256     // hidden
#define NC 9       // classes
#define G4 1024    // 4*H gates (one direction)
#define TCLOG 7
#define TC 128     // time chunk
#define NCH (SS / TC)

#define KV 20      // k4 chunks (of 4 k) cached in VGPR per gate type
#define KL 9       // k4 chunks cached in LDS per gate type
// streamed: k4 in [KV+KL, 64)

// ---------- activations (overflow-safe, fast) ----------
__device__ __forceinline__ float sigf(float x) {
    return 1.0f / (1.0f + __expf(-x));
}
__device__ __forceinline__ float tanhfast(float x) {
    float a = fabsf(x);
    float e = __expf(-2.0f * a);
    float t = (1.0f - e) / (1.0f + e);
    return copysignf(t, x);
}
__device__ __forceinline__ float dot4(float4 w, float4 h, float a) {
    a = fmaf(w.x, h.x, a); a = fmaf(w.y, h.y, a);
    a = fmaf(w.z, h.z, a); a = fmaf(w.w, h.w, a);
    return a;
}

// ---------- transpose w_hh -> wT[dir][k4][j][4] ----------
__global__ void transpose_whh(const float* __restrict__ whh, float* __restrict__ wT) {
    // whh: [2][1024][256] ; wT: [2][64][1024][4]
    int idx = blockIdx.x * 256 + threadIdx.x;
    if (idx >= 2 * 64 * 1024) return;
    int jj  = idx & 1023;
    int k4  = (idx >> 10) & 63;
    int dir = idx >> 16;
    float4 v = *(const float4*)(whh + ((long)(dir * 1024 + jj)) * 256 + (k4 << 2));
    *(float4*)(wT + (((long)(dir * 64 + k4)) * 1024 + jj) * 4) = v;
}

// ---------- tiled f32 GEMM (proven round-3): out[m][n] = A . W[n] + bias ----------
template <int KDIM, bool GATHER>
__global__ __launch_bounds__(256) void gemm_xg(
    const float* __restrict__ A, const int* __restrict__ tokens,
    const float* __restrict__ W, const float* __restrict__ bias,
    float* __restrict__ out, int t_base, int t_sign)
{
    __shared__ float As[16][68];
    __shared__ float Bs[16][68];
    const int tid = threadIdx.x;
    const int m0 = blockIdx.x * 64;
    const int n0 = blockIdx.y * 64;

    const int lr = tid >> 2;
    const int lk = (tid & 3) * 4;
    const int mload = m0 + lr;
    const int tcc = mload & (TC - 1);
    const int b   = mload >> TCLOG;
    const int tglob = t_base + t_sign * tcc;
    const long arow = (long)b * SS + tglob;
    const float* Ap = GATHER ? (A + (long)tokens[arow] * KDIM + lk)
                             : (A + arow * (long)KDIM + lk);
    const float* Wp = W + (long)(n0 + lr) * KDIM + lk;

    const int tr = tid >> 4;
    const int tn = tid & 15;

    float acc[4][4];
    #pragma unroll
    for (int i = 0; i < 4; i++)
        #pragma unroll
        for (int j = 0; j < 4; j++) acc[i][j] = 0.f;

    #pragma unroll 1
    for (int k0 = 0; k0 < KDIM; k0 += 16) {
        float4 av = *(const float4*)(Ap + k0);
        float4 bv = *(const float4*)(Wp + k0);
        As[lk + 0][lr] = av.x; As[lk + 1][lr] = av.y;
        As[lk + 2][lr] = av.z; As[lk + 3][lr] = av.w;
        Bs[lk + 0][lr] = bv.x; Bs[lk + 1][lr] = bv.y;
        Bs[lk + 2][lr] = bv.z; Bs[lk + 3][lr] = bv.w;
        __syncthreads();
        #pragma unroll
        for (int kk = 0; kk < 16; kk++) {
            float a[4], w[4];
            *(float4*)a = *(const float4*)&As[kk][tr * 4];
            *(float4*)w = *(const float4*)&Bs[kk][tn * 4];
            #pragma unroll
            for (int i = 0; i < 4; i++)
                #pragma unroll
                for (int j = 0; j < 4; j++) acc[i][j] = fmaf(a[i], w[j], acc[i][j]);
        }
        __syncthreads();
    }

    float4 bc = *(const float4*)(bias + n0 + tn * 4);
    #pragma unroll
    for (int i = 0; i < 4; i++) {
        float4 r;
        r.x = acc[i][0] + bc.x; r.y = acc[i][1] + bc.y;
        r.z = acc[i][2] + bc.z; r.w = acc[i][3] + bc.w;
        *(float4*)(out + (long)(m0 + tr * 4 + i) * G4 + n0 + tn * 4) = r;
    }
}

// ---------- hybrid cached LSTM scan ----------
// Grid (64 batch, 2 dir), 256 threads (4 waves = 1/SIMD -> 512 VGPR budget).
// Thread j owns h-column j: gate rows j, j+256, j+512, j+768.
// Weights: k4 [0,KV) in VGPR, [KV,KV+KL) in LDS, rest streamed from L2.
// h double-buffered in LDS -> one __syncthreads per step.
__global__ __launch_bounds__(256, 1) void lstm_cscan(
    const float* __restrict__ xgF, const float* __restrict__ xgB, // [B][TC][1024]
    const float* __restrict__ wT,     // [2][64][1024][4]
    const float* __restrict__ bhh2,   // [2][1024]
    float* __restrict__ hout,         // [B*S][512]
    float* __restrict__ state,        // [2][B][2][256]
    int tbF, int tbB, int doInit)
{
    const int b = blockIdx.x;
    const int d = blockIdx.y;
    const int j = threadIdx.x;
    const float* xg = (d ? xgB : xgF) + (long)b * TC * G4;
    const float* wTd = wT + (long)d * 64 * G4 * 4;

    __shared__ float4 hl[2][64];                 // 2 KB, double-buffered h
    __shared__ float4 lw[KL * 4 * 256];          // 147.5 KB weight cache

    // ---- VGPR weight cache: k4 in [0,KV), all 4 gate types ----
    float4 wv0[KV], wv1[KV], wv2[KV], wv3[KV];
    #pragma unroll
    for (int k4 = 0; k4 < KV; k4++) {
        const float4* p = (const float4*)(wTd + ((long)k4 * G4) * 4);
        wv0[k4] = p[j];
        wv1[k4] = p[j + 256];
        wv2[k4] = p[j + 512];
        wv3[k4] = p[j + 768];
    }
    // ---- LDS weight cache: k4 in [KV, KV+KL) ----
    #pragma unroll
    for (int kk = 0; kk < KL; kk++) {
        const float4* p = (const float4*)(wTd + ((long)(KV + kk) * G4) * 4);
        lw[(kk * 4 + 0) * 256 + j] = p[j];
        lw[(kk * 4 + 1) * 256 + j] = p[j + 256];
        lw[(kk * 4 + 2) * 256 + j] = p[j + 512];
        lw[(kk * 4 + 3) * 256 + j] = p[j + 768];
    }

    const float b0 = bhh2[d * G4 + j];
    const float b1 = bhh2[d * G4 + j + 256];
    const float b2 = bhh2[d * G4 + j + 512];
    const float b3 = bhh2[d * G4 + j + 768];

    float c_reg = 0.f;
    if (doInit) {
        ((float*)hl[0])[j] = 0.f;
    } else {
        ((float*)hl[0])[j] = state[((d * BB + b) * 2 + 0) * HH + j];
        c_reg               = state[((d * BB + b) * 2 + 1) * HH + j];
    }
    __syncthreads();   // covers hl init + lw fill

    #pragma unroll 1
    for (int tc = 0; tc < TC; ++tc) {
        const int rb = tc & 1;
        const float4* hcur = hl[rb];
        float a0 = xg[tc * G4 + j      ] + b0;
        float a1 = xg[tc * G4 + j + 256] + b1;
        float a2 = xg[tc * G4 + j + 512] + b2;
        float a3 = xg[tc * G4 + j + 768] + b3;

        // VGPR-cached part
        #pragma unroll
        for (int k4 = 0; k4 < KV; k4++) {
            float4 h4 = hcur[k4];
            a0 = dot4(wv0[k4], h4, a0);
            a1 = dot4(wv1[k4], h4, a1);
            a2 = dot4(wv2[k4], h4, a2);
            a3 = dot4(wv3[k4], h4, a3);
        }
        // LDS-cached part (consecutive-j float4 reads: conflict-free)
        #pragma unroll
        for (int kk = 0; kk < KL; kk++) {
            float4 h4 = hcur[KV + kk];
            float4 w0 = lw[(kk * 4 + 0) * 256 + j];
            float4 w1 = lw[(kk * 4 + 1) * 256 + j];
            float4 w2 = lw[(kk * 4 + 2) * 256 + j];
            float4 w3 = lw[(kk * 4 + 3) * 256 + j];
            a0 = dot4(w0, h4, a0);
            a1 = dot4(w1, h4, a1);
            a2 = dot4(w2, h4, a2);
            a3 = dot4(w3, h4, a3);
        }
        // L2-streamed part
        #pragma unroll 5
        for (int k4 = KV + KL; k4 < 64; k4++) {
            float4 h4 = hcur[k4];
            const float4* p = (const float4*)(wTd + ((long)k4 * G4) * 4);
            float4 w0 = p[j];
            float4 w1 = p[j + 256];
            float4 w2 = p[j + 512];
            float4 w3 = p[j + 768];
            a0 = dot4(w0, h4, a0);
            a1 = dot4(w1, h4, a1);
            a2 = dot4(w2, h4, a2);
            a3 = dot4(w3, h4, a3);
        }

        // gate order: i, f, g, o
        c_reg = sigf(a1) * c_reg + sigf(a0) * tanhfast(a2);
        float h = sigf(a3) * tanhfast(c_reg);
        ((float*)hl[rb ^ 1])[j] = h;
        const int t = d ? (tbB - tc) : (tbF + tc);
        hout[((long)(b * SS + t)) * 512 + d * HH + j] = h;
        __syncthreads();   // next step reads hl[rb^1]; frees hl[rb] for write
    }

    state[((d * BB + b) * 2 + 0) * HH + j] = ((float*)hl[TC & 1])[j];
    state[((d * BB + b) * 2 + 1) * HH + j] = c_reg;
}

// ---------- emissions ----------
__global__ __launch_bounds__(256) void emissions_k(
    const float* __restrict__ h1, const float* __restrict__ clsw,
    const float* __restrict__ clsb, float* __restrict__ em)
{
    long u = (long)blockIdx.x * 256 + threadIdx.x;
    if (u >= (long)BB * SS * NC) return;
    int c = (int)(u % NC);
    long m = u / NC;
    const float4* hr = (const float4*)(h1 + m * 512);
    const float4* wr = (const float4*)(clsw + (long)c * 512);
    float s0 = 0, s1 = 0, s2 = 0, s3 = 0;
    #pragma unroll 8
    for (int q = 0; q < 128; q += 4) {
        float4 a0 = hr[q],     w0 = wr[q];
        float4 a1 = hr[q + 1], w1 = wr[q + 1];
        float4 a2 = hr[q + 2], w2 = wr[q + 2];
        float4 a3 = hr[q + 3], w3 = wr[q + 3];
        s0 += a0.x * w0.x + a0.y * w0.y + a0.z * w0.z + a0.w * w0.w;
        s1 += a1.x * w1.x + a1.y * w1.y + a1.z * w1.z + a1.w * w1.w;
        s2 += a2.x * w2.x + a2.y * w2.y + a2.z * w2.z + a2.w * w2.w;
        s3 += a3.x * w3.x + a3.y * w3.y + a3.z * w3.z + a3.w * w3.w;
    }
    em[u] = (s0 + s1) + (s2 + s3) + clsb[c];
}

// ---------- CRF log-likelihood per batch row ----------
__global__ __launch_bounds__(64) void crf_llh(
    const float* __restrict__ em, const int* __restrict__ labels,
    const int* __restrict__ mask, const float* __restrict__ start,
    const float* __restrict__ endt, const float* __restrict__ trans,
    float* __restrict__ llh)
{
    int b = blockIdx.x, j = threadIdx.x;
    bool act = j < NC;
    float tcol[NC];
    #pragma unroll
    for (int i = 0; i < NC; i++) tcol[i] = act ? trans[i * NC + j] : 0.f;
    const float* emb_ = em + (long)b * SS * NC;
    const int* lb = labels + b * SS;
    const int* mk = mask + b * SS;
    float alpha = act ? (start[j] + emb_[j]) : -1e30f;

    float num = 0.f;
    int msum = 0;
    for (int t = j; t < SS; t += 64) msum += (mk[t] != 0);
    for (int t = 1 + j; t < SS; t += 64) {
        float m = (float)mk[t];
        num += m * (trans[lb[t - 1] * NC + lb[t]] + emb_[t * NC + lb[t]]);
    }
    for (int o = 32; o > 0; o >>= 1) {
        num  += __shfl_down(num, o);
        msum += __shfl_down(msum, o);
    }
    msum = __shfl(msum, 0);

    for (int t = 1; t < SS; t++) {
        int m = mk[t];
        float emj = act ? emb_[t * NC + j] : 0.f;
        float v[NC];
        float mx = -1e30f;
        #pragma unroll
        for (int i = 0; i < NC; i++) {
            v[i] = __shfl(alpha, i) + tcol[i];
            mx = fmaxf(mx, v[i]);
        }
        float sum = 0.f;
        #pragma unroll
        for (int i = 0; i < NC; i++) sum += __expf(v[i] - mx);
        float nxt = mx + __logf(sum) + emj;
        if (m > 0 && act) alpha = nxt;
    }
    float fin = act ? alpha + endt[j] : -1e30f;
    float mx = -1e30f;
    #pragma unroll
    for (int i = 0; i < NC; i++) mx = fmaxf(mx, __shfl(fin, i));
    float s = 0.f;
    #pragma unroll
    for (int i = 0; i < NC; i++) s += __expf(__shfl(fin, i) - mx);
    float den = mx + __logf(s);
    if (j == 0) {
        int last_idx = msum - 1;
        float numer = num + start[lb[0]] + emb_[lb[0]] + endt[lb[last_idx]];
        llh[b] = numer - den;
    }
}

__global__ __launch_bounds__(64) void loss_k(const float* __restrict__ llh, float* __restrict__ out) {
    int j = threadIdx.x;
    float v = llh[j];
    for (int o = 32; o > 0; o >>= 1) v += __shfl_down(v, o);
    if (j == 0) out[0] = -v / 64.0f;
}

// ---------- Viterbi per batch row ----------
__global__ __launch_bounds__(64) void viterbi_k(
    const float* __restrict__ em, const int* __restrict__ mask,
    const float* __restrict__ start, const float* __restrict__ endt,
    const float* __restrict__ trans, float* __restrict__ outp)
{
    int b = blockIdx.x, j = threadIdx.x;
    bool act = j < NC;
    __shared__ unsigned char bp[SS][NC];
    float tcol[NC];
    #pragma unroll
    for (int i = 0; i < NC; i++) tcol[i] = act ? trans[i * NC + j] : 0.f;
    const float* emb_ = em + (long)b * SS * NC;
    const int* mk = mask + b * SS;
    float score = act ? (start[j] + emb_[j]) : -1e30f;

    for (int t = 1; t < SS; t++) {
        float best = 0.f;
        int bi = 0;
        #pragma unroll
        for (int i = 0; i < NC; i++) {
            float vv = __shfl(score, i) + tcol[i];
            if (i == 0 || vv > best) { best = vv; bi = i; }   // first-max (jnp.argmax)
        }
        int m = mk[t];
        float nxt = best + (act ? emb_[t * NC + j] : 0.f);
        if (act) {
            if (m > 0) { score = nxt; bp[t][j] = (unsigned char)bi; }
            else       { bp[t][j] = (unsigned char)j; }
        }
    }
    float fin = act ? score + endt[j] : -1e30f;
    float bestf = 0.f;
    int last = 0;
    #pragma unroll
    for (int i = 0; i < NC; i++) {
        float vv = __shfl(fin, i);
        if (i == 0 || vv > bestf) { bestf = vv; last = i; }
    }
    __syncthreads();
    if (j == 0) {
        int cur = last;
        outp[1 + (long)b * SS + (SS - 1)] = (float)cur;
        for (int t = SS - 1; t >= 1; t--) {
            cur = bp[t][cur];
            outp[1 + (long)b * SS + (t - 1)] = (float)cur;
        }
    }
}

extern "C" void kernel_launch(void* const* d_in, const int* in_sizes, int n_in,
                              void* d_out, int out_size, void* d_ws, size_t ws_size,
                              hipStream_t stream) {
    const int*   tok    = (const int*)d_in[0];
    const int*   lab    = (const int*)d_in[1];
    const int*   msk    = (const int*)d_in[2];
    const float* emb    = (const float*)d_in[3];
    const float* w_ih0  = (const float*)d_in[4];   // (2,1024,128)
    const float* w_hh0  = (const float*)d_in[5];   // (2,1024,256)
    const float* b_ih0  = (const float*)d_in[6];   // (2,1024)
    const float* b_hh0  = (const float*)d_in[7];
    const float* w_ih1  = (const float*)d_in[8];   // (2,1024,512)
    const float* w_hh1  = (const float*)d_in[9];
    const float* b_ih1  = (const float*)d_in[10];
    const float* b_hh1  = (const float*)d_in[11];
    const float* clsw   = (const float*)d_in[12];  // (9,512)
    const float* clsb   = (const float*)d_in[13];
    const float* startt = (const float*)d_in[14];
    const float* endt   = (const float*)d_in[15];
    const float* transm = (const float*)d_in[16];
    float* out = (float*)d_out;

    // ---- workspace carve (f32 elements); ~205 MB (round-3-proven footprint) ----
    size_t nH  = (size_t)BB * SS * 512;            // 16.78M each
    size_t nWT = (size_t)2 * 64 * 1024 * 4;        // 0.52M per layer
    size_t nEM = (size_t)BB * SS * NC;
    size_t nST = (size_t)2 * BB * 2 * HH;
    size_t nXG = (size_t)BB * TC * G4;             // 8.39M each dir

    float* H0  = (float*)d_ws;
    float* H1  = H0 + nH;
    float* WT0 = H1 + nH;
    float* WT1 = WT0 + nWT;
    float* EM  = WT1 + nWT;
    float* ST  = EM + nEM;
    float* LLH = ST + nST;
    float* XGF = LLH + 64;
    float* XGB = XGF + nXG;

    transpose_whh<<<512, 256, 0, stream>>>(w_hh0, WT0);
    transpose_whh<<<512, 256, 0, stream>>>(w_hh1, WT1);

    dim3 gg((BB * TC) / 64, G4 / 64);    // (128, 16)
    dim3 rg(BB, 2);                      // 128 blocks, 256 threads

    // ---- layer 0 ----
    for (int c = 0; c < NCH; c++) {
        int tbF = c * TC;
        int tbB = SS - 1 - c * TC;
        gemm_xg<128, true><<<gg, 256, 0, stream>>>(emb, tok, w_ih0,              b_ih0,        XGF, tbF, +1);
        gemm_xg<128, true><<<gg, 256, 0, stream>>>(emb, tok, w_ih0 + 1024 * 128, b_ih0 + 1024, XGB, tbB, -1);
        lstm_cscan<<<rg, 256, 0, stream>>>(XGF, XGB, WT0, b_hh0, H0, ST, tbF, tbB, c == 0);
    }
    // ---- layer 1 ----
    for (int c = 0; c < NCH; c++) {
        int tbF = c * TC;
        int tbB = SS - 1 - c * TC;
        gemm_xg<512, false><<<gg, 256, 0, stream>>>(H0, nullptr, w_ih1,              b_ih1,        XGF, tbF, +1);
        gemm_xg<512, false><<<gg, 256, 0, stream>>>(H0, nullptr, w_ih1 + 1024 * 512, b_ih1 + 1024, XGB, tbB, -1);
        lstm_cscan<<<rg, 256, 0, stream>>>(XGF, XGB, WT1, b_hh1, H1, ST, tbF, tbB, c == 0);
    }

    emissions_k<<<((BB * SS * NC) + 255) / 256, 256, 0, stream>>>(H1, clsw, clsb, EM);
    crf_llh<<<BB, 64, 0, stream>>>(EM, lab, msk, startt, endt, transm, LLH);
    loss_k<<<1, 64, 0, stream>>>(LLH, out);
    viterbi_k<<<BB, 64, 0, stream>>>(EM, msk, startt, endt, transm, out);
}

// Round 8
// 7709.605 us; speedup vs baseline: 2.5986x; 1.8280x over previous
//
#include <hip/hip_runtime.h>
#include <math.h>

#define BB 64      // batch
#define SS 512     // seq len
#define EE 128     // embed dim
#define HH 256     // hidden
#define NC 9       // classes
#define G4 1024    // 4*H gates (one direction)
#define TCLOG 7
#define TC 128     // time chunk
#define NCH (SS / TC)

#define KV 20      // k4 chunks cached in VGPR (per gate row) = 80 regs/thread
#define KL 9       // k4 chunks cached in LDS = 144 KB
// streamed: k4 in [KV+KL, 64) = 35 chunks = 560 KB/step

// ---------- activations (overflow-safe, fast) ----------
__device__ __forceinline__ float sigf(float x) {
    return 1.0f / (1.0f + __expf(-x));
}
__device__ __forceinline__ float tanhfast(float x) {
    float a = fabsf(x);
    float e = __expf(-2.0f * a);
    float t = (1.0f - e) / (1.0f + e);
    return copysignf(t, x);
}
__device__ __forceinline__ float dot4(float4 w, float4 h, float a) {
    a = fmaf(w.x, h.x, a); a = fmaf(w.y, h.y, a);
    a = fmaf(w.z, h.z, a); a = fmaf(w.w, h.w, a);
    return a;
}

// ---------- transpose w_hh -> wT[dir][k4][j][4] ----------
__global__ void transpose_whh(const float* __restrict__ whh, float* __restrict__ wT) {
    // whh: [2][1024][256] ; wT: [2][64][1024][4]
    int idx = blockIdx.x * 256 + threadIdx.x;
    if (idx >= 2 * 64 * 1024) return;
    int jj  = idx & 1023;
    int k4  = (idx >> 10) & 63;
    int dir = idx >> 16;
    float4 v = *(const float4*)(whh + ((long)(dir * 1024 + jj)) * 256 + (k4 << 2));
    *(float4*)(wT + (((long)(dir * 64 + k4)) * 1024 + jj) * 4) = v;
}

// ---------- tiled f32 GEMM (proven round-3): out[m][n] = A . W[n] + bias ----------
template <int KDIM, bool GATHER>
__global__ __launch_bounds__(256) void gemm_xg(
    const float* __restrict__ A, const int* __restrict__ tokens,
    const float* __restrict__ W, const float* __restrict__ bias,
    float* __restrict__ out, int t_base, int t_sign)
{
    __shared__ float As[16][68];
    __shared__ float Bs[16][68];
    const int tid = threadIdx.x;
    const int m0 = blockIdx.x * 64;
    const int n0 = blockIdx.y * 64;

    const int lr = tid >> 2;
    const int lk = (tid & 3) * 4;
    const int mload = m0 + lr;
    const int tcc = mload & (TC - 1);
    const int b   = mload >> TCLOG;
    const int tglob = t_base + t_sign * tcc;
    const long arow = (long)b * SS + tglob;
    const float* Ap = GATHER ? (A + (long)tokens[arow] * KDIM + lk)
                             : (A + arow * (long)KDIM + lk);
    const float* Wp = W + (long)(n0 + lr) * KDIM + lk;

    const int tr = tid >> 4;
    const int tn = tid & 15;

    float acc[4][4];
    #pragma unroll
    for (int i = 0; i < 4; i++)
        #pragma unroll
        for (int j = 0; j < 4; j++) acc[i][j] = 0.f;

    #pragma unroll 1
    for (int k0 = 0; k0 < KDIM; k0 += 16) {
        float4 av = *(const float4*)(Ap + k0);
        float4 bv = *(const float4*)(Wp + k0);
        As[lk + 0][lr] = av.x; As[lk + 1][lr] = av.y;
        As[lk + 2][lr] = av.z; As[lk + 3][lr] = av.w;
        Bs[lk + 0][lr] = bv.x; Bs[lk + 1][lr] = bv.y;
        Bs[lk + 2][lr] = bv.z; Bs[lk + 3][lr] = bv.w;
        __syncthreads();
        #pragma unroll
        for (int kk = 0; kk < 16; kk++) {
            float a[4], w[4];
            *(float4*)a = *(const float4*)&As[kk][tr * 4];
            *(float4*)w = *(const float4*)&Bs[kk][tn * 4];
            #pragma unroll
            for (int i = 0; i < 4; i++)
                #pragma unroll
                for (int j = 0; j < 4; j++) acc[i][j] = fmaf(a[i], w[j], acc[i][j]);
        }
        __syncthreads();
    }

    float4 bc = *(const float4*)(bias + n0 + tn * 4);
    #pragma unroll
    for (int i = 0; i < 4; i++) {
        float4 r;
        r.x = acc[i][0] + bc.x; r.y = acc[i][1] + bc.y;
        r.z = acc[i][2] + bc.z; r.w = acc[i][3] + bc.w;
        *(float4*)(out + (long)(m0 + tr * 4 + i) * G4 + n0 + tn * 4) = r;
    }
}

// ---------- hybrid cached LSTM scan v2 ----------
// Grid (64 batch, 2 dir), 1024 threads (16 waves = 4/SIMD -> latency hiding).
// Thread j owns gate row j: 64 float4 weights.
//   k4 [0,KV)      -> VGPR (80 regs/thread, 320 KB/CU)
//   k4 [KV,KV+KL)  -> LDS  (144 KB, conflict-free [kk][j] float4)
//   k4 [KV+KL,64)  -> streamed from L2 (560 KB/step)
// gl exchange + double-buffered h: 2 barriers/step (round-3-proven pattern).
__global__ __launch_bounds__(1024, 4) void lstm_cscan2(
    const float* __restrict__ xgF, const float* __restrict__ xgB, // [B][TC][1024]
    const float* __restrict__ wT,     // [2][64][1024][4]
    const float* __restrict__ bhh2,   // [2][1024]
    float* __restrict__ hout,         // [B*S][512]
    float* __restrict__ state,        // [2][B][2][256]
    int tbF, int tbB, int doInit)
{
    const int b = blockIdx.x;
    const int d = blockIdx.y;
    const int j = threadIdx.x;
    const float* xg  = (d ? xgB : xgF) + (long)b * TC * G4 + j;
    const float* wTd = wT + (long)d * 64 * G4 * 4;

    __shared__ float4 hl[2][64];        // 2 KB double-buffered h
    __shared__ float  gl[G4];           // 4 KB gate exchange
    __shared__ float4 lw[KL * 1024];    // 144 KB weight cache

    // ---- VGPR weight cache: k4 in [0,KV) ----
    float4 wv[KV];
    #pragma unroll
    for (int k4 = 0; k4 < KV; k4++)
        wv[k4] = *(const float4*)(wTd + ((long)k4 * G4 + j) * 4);
    // ---- LDS weight cache: k4 in [KV,KV+KL) ----
    #pragma unroll
    for (int kk = 0; kk < KL; kk++)
        lw[kk * 1024 + j] = *(const float4*)(wTd + ((long)(KV + kk) * G4 + j) * 4);

    const float bj = bhh2[d * G4 + j];
    float c_reg = 0.f;
    if (doInit) {
        if (j < HH) ((float*)hl[0])[j] = 0.f;
    } else {
        if (j < HH) {
            ((float*)hl[0])[j] = state[((d * BB + b) * 2 + 0) * HH + j];
            c_reg               = state[((d * BB + b) * 2 + 1) * HH + j];
        }
    }
    __syncthreads();   // covers hl init + lw fill

    #pragma unroll 1
    for (int tc = 0; tc < TC; ++tc) {
        const int rb = tc & 1;
        const float4* hcur = hl[rb];
        float acc = xg[(long)tc * G4] + bj;

        // VGPR-cached part
        #pragma unroll
        for (int k4 = 0; k4 < KV; k4++)
            acc = dot4(wv[k4], hcur[k4], acc);
        // LDS-cached part (lane-consecutive float4: conflict-free)
        #pragma unroll
        for (int kk = 0; kk < KL; kk++)
            acc = dot4(lw[kk * 1024 + j], hcur[KV + kk], acc);
        // L2-streamed part
        #pragma unroll 5
        for (int k4 = KV + KL; k4 < 64; k4++) {
            float4 w = *(const float4*)(wTd + ((long)k4 * G4 + j) * 4);
            acc = dot4(w, hcur[k4], acc);
        }

        gl[j] = acc;
        __syncthreads();
        if (j < HH) {
            float gi = gl[j], gf = gl[j + 256], gg = gl[j + 512], go = gl[j + 768];
            c_reg = sigf(gf) * c_reg + sigf(gi) * tanhfast(gg);
            float h = sigf(go) * tanhfast(c_reg);
            ((float*)hl[rb ^ 1])[j] = h;
            const int t = d ? (tbB - tc) : (tbF + tc);
            hout[((long)(b * SS + t)) * 512 + d * HH + j] = h;
        }
        __syncthreads();
    }

    if (j < HH) {
        state[((d * BB + b) * 2 + 0) * HH + j] = ((float*)hl[TC & 1])[j];
        state[((d * BB + b) * 2 + 1) * HH + j] = c_reg;
    }
}

// ---------- emissions ----------
__global__ __launch_bounds__(256) void emissions_k(
    const float* __restrict__ h1, const float* __restrict__ clsw,
    const float* __restrict__ clsb, float* __restrict__ em)
{
    long u = (long)blockIdx.x * 256 + threadIdx.x;
    if (u >= (long)BB * SS * NC) return;
    int c = (int)(u % NC);
    long m = u / NC;
    const float4* hr = (const float4*)(h1 + m * 512);
    const float4* wr = (const float4*)(clsw + (long)c * 512);
    float s0 = 0, s1 = 0, s2 = 0, s3 = 0;
    #pragma unroll 8
    for (int q = 0; q < 128; q += 4) {
        float4 a0 = hr[q],     w0 = wr[q];
        float4 a1 = hr[q + 1], w1 = wr[q + 1];
        float4 a2 = hr[q + 2], w2 = wr[q + 2];
        float4 a3 = hr[q + 3], w3 = wr[q + 3];
        s0 += a0.x * w0.x + a0.y * w0.y + a0.z * w0.z + a0.w * w0.w;
        s1 += a1.x * w1.x + a1.y * w1.y + a1.z * w1.z + a1.w * w1.w;
        s2 += a2.x * w2.x + a2.y * w2.y + a2.z * w2.z + a2.w * w2.w;
        s3 += a3.x * w3.x + a3.y * w3.y + a3.z * w3.z + a3.w * w3.w;
    }
    em[u] = (s0 + s1) + (s2 + s3) + clsb[c];
}

// ---------- CRF log-likelihood per batch row ----------
__global__ __launch_bounds__(64) void crf_llh(
    const float* __restrict__ em, const int* __restrict__ labels,
    const int* __restrict__ mask, const float* __restrict__ start,
    const float* __restrict__ endt, const float* __restrict__ trans,
    float* __restrict__ llh)
{
    int b = blockIdx.x, j = threadIdx.x;
    bool act = j < NC;
    float tcol[NC];
    #pragma unroll
    for (int i = 0; i < NC; i++) tcol[i] = act ? trans[i * NC + j] : 0.f;
    const float* emb_ = em + (long)b * SS * NC;
    const int* lb = labels + b * SS;
    const int* mk = mask + b * SS;
    float alpha = act ? (start[j] + emb_[j]) : -1e30f;

    float num = 0.f;
    int msum = 0;
    for (int t = j; t < SS; t += 64) msum += (mk[t] != 0);
    for (int t = 1 + j; t < SS; t += 64) {
        float m = (float)mk[t];
        num += m * (trans[lb[t - 1] * NC + lb[t]] + emb_[t * NC + lb[t]]);
    }
    for (int o = 32; o > 0; o >>= 1) {
        num  += __shfl_down(num, o);
        msum += __shfl_down(msum, o);
    }
    msum = __shfl(msum, 0);

    for (int t = 1; t < SS; t++) {
        int m = mk[t];
        float emj = act ? emb_[t * NC + j] : 0.f;
        float v[NC];
        float mx = -1e30f;
        #pragma unroll
        for (int i = 0; i < NC; i++) {
            v[i] = __shfl(alpha, i) + tcol[i];
            mx = fmaxf(mx, v[i]);
        }
        float sum = 0.f;
        #pragma unroll
        for (int i = 0; i < NC; i++) sum += __expf(v[i] - mx);
        float nxt = mx + __logf(sum) + emj;
        if (m > 0 && act) alpha = nxt;
    }
    float fin = act ? alpha + endt[j] : -1e30f;
    float mx = -1e30f;
    #pragma unroll
    for (int i = 0; i < NC; i++) mx = fmaxf(mx, __shfl(fin, i));
    float s = 0.f;
    #pragma unroll
    for (int i = 0; i < NC; i++) s += __expf(__shfl(fin, i) - mx);
    float den = mx + __logf(s);
    if (j == 0) {
        int last_idx = msum - 1;
        float numer = num + start[lb[0]] + emb_[lb[0]] + endt[lb[last_idx]];
        llh[b] = numer - den;
    }
}

__global__ __launch_bounds__(64) void loss_k(const float* __restrict__ llh, float* __restrict__ out) {
    int j = threadIdx.x;
    float v = llh[j];
    for (int o = 32; o > 0; o >>= 1) v += __shfl_down(v, o);
    if (j == 0) out[0] = -v / 64.0f;
}

// ---------- Viterbi per batch row ----------
__global__ __launch_bounds__(64) void viterbi_k(
    const float* __restrict__ em, const int* __restrict__ mask,
    const float* __restrict__ start, const float* __restrict__ endt,
    const float* __restrict__ trans, float* __restrict__ outp)
{
    int b = blockIdx.x, j = threadIdx.x;
    bool act = j < NC;
    __shared__ unsigned char bp[SS][NC];
    float tcol[NC];
    #pragma unroll
    for (int i = 0; i < NC; i++) tcol[i] = act ? trans[i * NC + j] : 0.f;
    const float* emb_ = em + (long)b * SS * NC;
    const int* mk = mask + b * SS;
    float score = act ? (start[j] + emb_[j]) : -1e30f;

    for (int t = 1; t < SS; t++) {
        float best = 0.f;
        int bi = 0;
        #pragma unroll
        for (int i = 0; i < NC; i++) {
            float vv = __shfl(score, i) + tcol[i];
            if (i == 0 || vv > best) { best = vv; bi = i; }   // first-max (jnp.argmax)
        }
        int m = mk[t];
        float nxt = best + (act ? emb_[t * NC + j] : 0.f);
        if (act) {
            if (m > 0) { score = nxt; bp[t][j] = (unsigned char)bi; }
            else       { bp[t][j] = (unsigned char)j; }
        }
    }
    float fin = act ? score + endt[j] : -1e30f;
    float bestf = 0.f;
    int last = 0;
    #pragma unroll
    for (int i = 0; i < NC; i++) {
        float vv = __shfl(fin, i);
        if (i == 0 || vv > bestf) { bestf = vv; last = i; }
    }
    __syncthreads();
    if (j == 0) {
        int cur = last;
        outp[1 + (long)b * SS + (SS - 1)] = (float)cur;
        for (int t = SS - 1; t >= 1; t--) {
            cur = bp[t][cur];
            outp[1 + (long)b * SS + (t - 1)] = (float)cur;
        }
    }
}

extern "C" void kernel_launch(void* const* d_in, const int* in_sizes, int n_in,
                              void* d_out, int out_size, void* d_ws, size_t ws_size,
                              hipStream_t stream) {
    const int*   tok    = (const int*)d_in[0];
    const int*   lab    = (const int*)d_in[1];
    const int*   msk    = (const int*)d_in[2];
    const float* emb    = (const float*)d_in[3];
    const float* w_ih0  = (const float*)d_in[4];   // (2,1024,128)
    const float* w_hh0  = (const float*)d_in[5];   // (2,1024,256)
    const float* b_ih0  = (const float*)d_in[6];   // (2,1024)
    const float* b_hh0  = (const float*)d_in[7];
    const float* w_ih1  = (const float*)d_in[8];   // (2,1024,512)
    const float* w_hh1  = (const float*)d_in[9];
    const float* b_ih1  = (const float*)d_in[10];
    const float* b_hh1  = (const float*)d_in[11];
    const float* clsw   = (const float*)d_in[12];  // (9,512)
    const float* clsb   = (const float*)d_in[13];
    const float* startt = (const float*)d_in[14];
    const float* endt   = (const float*)d_in[15];
    const float* transm = (const float*)d_in[16];
    float* out = (float*)d_out;

    // ---- workspace carve (f32 elements); ~205 MB (round-3-proven footprint) ----
    size_t nH  = (size_t)BB * SS * 512;            // 16.78M each
    size_t nWT = (size_t)2 * 64 * 1024 * 4;        // 0.52M per layer
    size_t nEM = (size_t)BB * SS * NC;
    size_t nST = (size_t)2 * BB * 2 * HH;
    size_t nXG = (size_t)BB * TC * G4;             // 8.39M each dir

    float* H0  = (float*)d_ws;
    float* H1  = H0 + nH;
    float* WT0 = H1 + nH;
    float* WT1 = WT0 + nWT;
    float* EM  = WT1 + nWT;
    float* ST  = EM + nEM;
    float* LLH = ST + nST;
    float* XGF = LLH + 64;
    float* XGB = XGF + nXG;

    transpose_whh<<<512, 256, 0, stream>>>(w_hh0, WT0);
    transpose_whh<<<512, 256, 0, stream>>>(w_hh1, WT1);

    dim3 gg((BB * TC) / 64, G4 / 64);    // (128, 16)
    dim3 rg(BB, 2);                      // 128 blocks, 1024 threads

    // ---- layer 0 ----
    for (int c = 0; c < NCH; c++) {
        int tbF = c * TC;
        int tbB = SS - 1 - c * TC;
        gemm_xg<128, true><<<gg, 256, 0, stream>>>(emb, tok, w_ih0,              b_ih0,        XGF, tbF, +1);
        gemm_xg<128, true><<<gg, 256, 0, stream>>>(emb, tok, w_ih0 + 1024 * 128, b_ih0 + 1024, XGB, tbB, -1);
        lstm_cscan2<<<rg, 1024, 0, stream>>>(XGF, XGB, WT0, b_hh0, H0, ST, tbF, tbB, c == 0);
    }
    // ---- layer 1 ----
    for (int c = 0; c < NCH; c++) {
        int tbF = c * TC;
        int tbB = SS - 1 - c * TC;
        gemm_xg<512, false><<<gg, 256, 0, stream>>>(H0, nullptr, w_ih1,              b_ih1,        XGF, tbF, +1);
        gemm_xg<512, false><<<gg, 256, 0, stream>>>(H0, nullptr, w_ih1 + 1024 * 512, b_ih1 + 1024, XGB, tbB, -1);
        lstm_cscan2<<<rg, 1024, 0, stream>>>(XGF, XGB, WT1, b_hh1, H1, ST, tbF, tbB, c == 0);
    }

    emissions_k<<<((BB * SS * NC) + 255) / 256, 256, 0, stream>>>(H1, clsw, clsb, EM);
    crf_llh<<<BB, 64, 0, stream>>>(EM, lab, msk, startt, endt, transm, LLH);
    loss_k<<<1, 64, 0, stream>>>(LLH, out);
    viterbi_k<<<BB, 64, 0, stream>>>(EM, msk, startt, endt, transm, out);
}